// Round 1
// baseline (1143.941 us; speedup 1.0000x reference)
//
#include <hip/hip_runtime.h>

#define C_DIM 256
#define P_DIM 2048
#define L_DIM 1024
#define N_DIM 16
#define KEEP 102
#define PIXB 16
#define TIE_CAP 40

// ---------------- kernel 1a: pinv[p] = 1/||pool_p|| ----------------
__global__ __launch_bounds__(256) void k_pinv(const float* __restrict__ pool,
                                              float* __restrict__ pinv) {
  int p = blockIdx.x * 256 + threadIdx.x;
  const float4* row = (const float4*)(pool + (size_t)p * C_DIM);
  float s = 0.f;
#pragma unroll
  for (int i = 0; i < C_DIM / 4; ++i) {
    float4 v = row[i];
    s += v.x * v.x + v.y * v.y + v.z * v.z + v.w * v.w;
  }
  pinv[p] = 1.0f / sqrtf(s);
}

// ------------- kernel 1b: poolTs[c][p] = pool[p][c] * pinv[p] -------------
__global__ __launch_bounds__(256) void k_transpose(const float* __restrict__ pool,
                                                   const float* __restrict__ pinv,
                                                   float* __restrict__ poolTs) {
  __shared__ float tile[32][33];
  __shared__ float pv[32];
  int bx = blockIdx.x & 63;   // p tile index (2048/32 = 64)
  int by = blockIdx.x >> 6;   // c tile index (256/32 = 8)
  int tx = threadIdx.x & 31, ty = threadIdx.x >> 5;
  int p0 = bx * 32, c0 = by * 32;
  if (threadIdx.x < 32) pv[threadIdx.x] = pinv[p0 + threadIdx.x];
#pragma unroll
  for (int k = 0; k < 4; ++k)
    tile[ty + 8 * k][tx] = pool[(size_t)(p0 + ty + 8 * k) * C_DIM + c0 + tx];
  __syncthreads();
#pragma unroll
  for (int k = 0; k < 4; ++k)
    poolTs[(size_t)(c0 + ty + 8 * k) * P_DIM + p0 + tx] = tile[tx][ty + 8 * k] * pv[tx];
}

// ---------------- main fused kernel ----------------
// grid = 1024 blocks (16 pixels each), 512 threads.
// thread (tp = t&255, th = t>>8): p-tile = [8*tp, 8*tp+8), pix-tile = [8*th, 8*th+8)
__device__ __forceinline__ unsigned unpack_cnt(const unsigned* a, int pix) {
  int half = pix >> 3, i = pix & 7;
  unsigned w = a[half * 4 + (i >> 1)];
  return (i & 1) ? (w >> 16) : (w & 0xffffu);
}

__global__ __launch_bounds__(512, 2) void k_main(const float* __restrict__ x,
                                                 const float* __restrict__ pool,
                                                 const float* __restrict__ poolTs,
                                                 float* __restrict__ out) {
  __shared__ float xs[C_DIM][PIXB];           // 16 KB  x tile [c][pix]
  __shared__ int2 kpw[PIXB][KEEP + 2];        // kept (p, bits(s)) lists
  __shared__ unsigned cntw[8];                // [half][4] packed 16-bit counts
  __shared__ unsigned cntGEs[8];
  __shared__ unsigned cntGTs[8];
  __shared__ unsigned kcnt[PIXB];
  __shared__ unsigned tie_cnt[PIXB];
  __shared__ int tie_p[PIXB][TIE_CAP];
  __shared__ unsigned char tie_keepf[PIXB][TIE_CAP];
  __shared__ float wsum[8][8];                // [wave][pixloc]
  __shared__ float invS[PIXB];

  const int t = threadIdx.x;
  const int tp = t & 255;
  const int th = t >> 8;
  const int lane = t & 63;
  const int wv = t >> 6;
  const int b = blockIdx.x;
  const int n = b >> 6;               // 64 blocks per image (1024 px / 16)
  const int l0 = (b & 63) * PIXB;

  // ---- stage x tile: xs[c][pix] = x[n][c][l0+pix] ----
  {
    int c = t >> 1, hf = t & 1;
    const float* src = x + ((size_t)(n * C_DIM + c) * L_DIM + l0 + hf * 8);
    float4 a = *(const float4*)src;
    float4 bb = *(const float4*)(src + 4);
    *(float4*)&xs[c][hf * 8] = a;
    *(float4*)&xs[c][hf * 8 + 4] = bb;
  }
  __syncthreads();

  // ---- phase 1: s[j][i] = sum_c poolTs[c][8tp+j] * xs[c][8th+i] ----
  float s[8][8];
#pragma unroll
  for (int j = 0; j < 8; ++j)
#pragma unroll
    for (int i = 0; i < 8; ++i) s[j][i] = 0.f;
  {
    const float* pT = poolTs + 8 * tp;
    const float* xrow = &xs[0][8 * th];
#pragma unroll 4
    for (int c = 0; c < C_DIM; ++c) {
      float4 pa = *(const float4*)(pT + (size_t)c * P_DIM);
      float4 pb = *(const float4*)(pT + (size_t)c * P_DIM + 4);
      float4 xa = *(const float4*)(xrow + c * PIXB);
      float4 xb = *(const float4*)(xrow + c * PIXB + 4);
      float pr[8] = {pa.x, pa.y, pa.z, pa.w, pb.x, pb.y, pb.z, pb.w};
      float xr[8] = {xa.x, xa.y, xa.z, xa.w, xb.x, xb.y, xb.z, xb.w};
#pragma unroll
      for (int j = 0; j < 8; ++j)
#pragma unroll
        for (int i = 0; i < 8; ++i) s[j][i] = fmaf(pr[j], xr[i], s[j][i]);
    }
  }

  // ---- phase 2: per-pixel threshold V = 102nd-largest |s| via 31-step
  //      binary search on the positive-float bit pattern (monotone in uint).
  //      Rounds 31/32 compute count(>=V) and count(>V) for tie handling. ----
  unsigned lo[8], hi[8], cGE[8], cGT[8];
#pragma unroll
  for (int i = 0; i < 8; ++i) { lo[i] = 0u; hi[i] = 0x7F800000u; }

  for (int round = 0; round < 33; ++round) {
    if (t < 8) cntw[t] = 0u;
    __syncthreads();
    unsigned um[8];
    float midf[8];
#pragma unroll
    for (int i = 0; i < 8; ++i) {
      unsigned m;
      if (round < 31) m = lo[i] + ((hi[i] - lo[i]) >> 1);
      else if (round == 31) m = lo[i];
      else m = lo[i] + 1u;
      um[i] = m;
      midf[i] = __uint_as_float(m);
    }
    unsigned cw[4] = {0u, 0u, 0u, 0u};
#pragma unroll
    for (int i = 0; i < 8; ++i) {
      unsigned c = 0;
#pragma unroll
      for (int j = 0; j < 8; ++j) c += (fabsf(s[j][i]) >= midf[i]) ? 1u : 0u;
      cw[i >> 1] += (i & 1) ? (c << 16) : c;
    }
#pragma unroll
    for (int off = 32; off > 0; off >>= 1) {
#pragma unroll
      for (int q = 0; q < 4; ++q) cw[q] += __shfl_down(cw[q], off);
    }
    if (lane == 0) {
#pragma unroll
      for (int q = 0; q < 4; ++q) atomicAdd(&cntw[th * 4 + q], cw[q]);
    }
    __syncthreads();
#pragma unroll
    for (int i = 0; i < 8; ++i) {
      unsigned w = cntw[th * 4 + (i >> 1)];
      unsigned cnt = (i & 1) ? (w >> 16) : (w & 0xffffu);
      if (round < 31) {
        if (cnt >= KEEP) lo[i] = um[i]; else hi[i] = um[i];
      } else if (round == 31) cGE[i] = cnt;
      else cGT[i] = cnt;
    }
    if (round == 31 && t < 8) cntGEs[t] = cntw[t];
    if (round == 32 && t < 8) cntGTs[t] = cntw[t];
    __syncthreads();
  }

  // ---- phase 3: inclusion mask + exact tie handling (ref keeps smallest p) ----
  if (t < PIXB) { kcnt[t] = 0u; tie_cnt[t] = 0u; }
  __syncthreads();

  unsigned incmask[8];
  bool slow[8];
#pragma unroll
  for (int i = 0; i < 8; ++i) {
    incmask[i] = 0u;
    float Vf = __uint_as_float(lo[i]);
    unsigned e = cGE[i] - cGT[i];
    unsigned r = (unsigned)KEEP - cGT[i];
    slow[i] = (e != r);
    int pix = 8 * th + i;
#pragma unroll
    for (int j = 0; j < 8; ++j) {
      float av = fabsf(s[j][i]);
      if (av > Vf) incmask[i] |= (1u << j);
      else if (av == Vf) {
        if (!slow[i]) incmask[i] |= (1u << j);
        else {
          unsigned idx = atomicAdd(&tie_cnt[pix], 1u);
          if (idx < TIE_CAP) tie_p[pix][idx] = 8 * tp + j;
        }
      }
    }
  }
  __syncthreads();

  if (t < PIXB) {  // resolve ties: keep r smallest indices among equals
    int pix = t;
    unsigned ge = unpack_cnt(cntGEs, pix);
    unsigned gt = unpack_cnt(cntGTs, pix);
    unsigned e = ge - gt, r = (unsigned)KEEP - gt;
    if (e != r) {
      unsigned tc = tie_cnt[pix]; if (tc > TIE_CAP) tc = TIE_CAP;
      for (unsigned k = 0; k < tc; ++k) tie_keepf[pix][k] = 0;
      unsigned rr = (r < tc) ? r : tc;
      for (unsigned k = 0; k < rr; ++k) {
        int best = -1, bp = 1 << 30;
        for (unsigned m = 0; m < tc; ++m)
          if (!tie_keepf[pix][m] && tie_p[pix][m] < bp) { bp = tie_p[pix][m]; best = (int)m; }
        if (best >= 0) tie_keepf[pix][best] = 1;
      }
    }
  }
  __syncthreads();

#pragma unroll
  for (int i = 0; i < 8; ++i) {
    if (slow[i]) {
      float Vf = __uint_as_float(lo[i]);
      int pix = 8 * th + i;
      unsigned tc = tie_cnt[pix]; if (tc > TIE_CAP) tc = TIE_CAP;
#pragma unroll
      for (int j = 0; j < 8; ++j) {
        if (fabsf(s[j][i]) == Vf) {
          int myp = 8 * tp + j;
          for (unsigned m = 0; m < tc; ++m)
            if (tie_p[pix][m] == myp && tie_keepf[pix][m]) incmask[i] |= (1u << j);
        }
      }
    }
  }

  // ---- phase 4: S = sum of kept s (signed), invS ----
  float ps[8];
#pragma unroll
  for (int i = 0; i < 8; ++i) {
    float a = 0.f;
#pragma unroll
    for (int j = 0; j < 8; ++j)
      if (incmask[i] & (1u << j)) a += s[j][i];
    ps[i] = a;
  }
#pragma unroll
  for (int off = 32; off > 0; off >>= 1) {
#pragma unroll
    for (int i = 0; i < 8; ++i) ps[i] += __shfl_down(ps[i], off);
  }
  if (lane == 0) {
#pragma unroll
    for (int i = 0; i < 8; ++i) wsum[wv][i] = ps[i];
  }
  __syncthreads();
  if (t < PIXB) {
    int pix = t, half = pix >> 3, i = pix & 7;
    float S = 0.f;
    for (int w = half * 4; w < half * 4 + 4; ++w) S += wsum[w][i];
    invS[pix] = 1.0f / S;
  }
  __syncthreads();

  // ---- phase 5: gather kept (p, s) into LDS lists ----
#pragma unroll
  for (int i = 0; i < 8; ++i) {
    int pix = 8 * th + i;
#pragma unroll
    for (int j = 0; j < 8; ++j) {
      if (incmask[i] & (1u << j)) {
        unsigned idx = atomicAdd(&kcnt[pix], 1u);
        if (idx < KEEP + 2) kpw[pix][idx] = make_int2(8 * tp + j, __float_as_int(s[j][i]));
      }
    }
  }
  __syncthreads();

  // ---- phase 6: reconstruct out[n][c][pix] = invS * sum_kept s_p * pool[p][c]
  //      thread handles c = tp for its 8 pixels; k-outer for 8-way MLP ----
  float oacc[8];
  unsigned kcs[8];
#pragma unroll
  for (int i = 0; i < 8; ++i) {
    oacc[i] = 0.f;
    unsigned kc = kcnt[8 * th + i];
    kcs[i] = kc < (unsigned)KEEP ? kc : (unsigned)KEEP;
  }
  const float* pbase = pool + tp;
#pragma unroll 2
  for (int k = 0; k < KEEP; ++k) {
#pragma unroll
    for (int i = 0; i < 8; ++i) {
      int pix = 8 * th + i;
      int2 e = kpw[pix][k];
      float pvv = pbase[(size_t)(e.x & (P_DIM - 1)) * C_DIM];
      if ((unsigned)k < kcs[i]) oacc[i] = fmaf(__int_as_float(e.y), pvv, oacc[i]);
    }
  }
#pragma unroll
  for (int i = 0; i < 8; ++i) oacc[i] *= invS[8 * th + i];
  float* dst = out + ((size_t)(n * C_DIM + tp) * L_DIM + l0 + 8 * th);
  *(float4*)dst = make_float4(oacc[0], oacc[1], oacc[2], oacc[3]);
  *(float4*)(dst + 4) = make_float4(oacc[4], oacc[5], oacc[6], oacc[7]);
}

// ---------------- launch ----------------
extern "C" void kernel_launch(void* const* d_in, const int* in_sizes, int n_in,
                              void* d_out, int out_size, void* d_ws, size_t ws_size,
                              hipStream_t stream) {
  const float* x = (const float*)d_in[0];
  const float* pool = (const float*)d_in[1];
  float* out = (float*)d_out;
  float* poolTs = (float*)d_ws;                       // 2048*256 f32 = 2 MB
  float* pinv = poolTs + (size_t)C_DIM * P_DIM;       // + 8 KB
  k_pinv<<<P_DIM / 256, 256, 0, stream>>>(pool, pinv);
  k_transpose<<<(P_DIM / 32) * (C_DIM / 32), 256, 0, stream>>>(pool, pinv, poolTs);
  k_main<<<(N_DIM * L_DIM) / PIXB, 512, 0, stream>>>(x, pool, poolTs, out);
}

// Round 2
// 776.441 us; speedup vs baseline: 1.4733x; 1.4733x over previous
//
#include <hip/hip_runtime.h>

#define C_DIM 256
#define P_DIM 2048
#define L_DIM 1024
#define N_DIM 16
#define KEEP 102
#define PIXB 16
#define TIE_CAP 40
#define HROW 260   // 256 bins + 4-bank skew per pixel row

// ---------------- kernel 1a: pinv[p] = 1/||pool_p|| ----------------
__global__ __launch_bounds__(256) void k_pinv(const float* __restrict__ pool,
                                              float* __restrict__ pinv) {
  int p = blockIdx.x * 256 + threadIdx.x;
  const float4* row = (const float4*)(pool + (size_t)p * C_DIM);
  float s = 0.f;
#pragma unroll
  for (int i = 0; i < C_DIM / 4; ++i) {
    float4 v = row[i];
    s += v.x * v.x + v.y * v.y + v.z * v.z + v.w * v.w;
  }
  pinv[p] = 1.0f / sqrtf(s);
}

// ------------- kernel 1b: poolTs[c][p] = pool[p][c] * pinv[p] -------------
__global__ __launch_bounds__(256) void k_transpose(const float* __restrict__ pool,
                                                   const float* __restrict__ pinv,
                                                   float* __restrict__ poolTs) {
  __shared__ float tile[32][33];
  __shared__ float pv[32];
  int bx = blockIdx.x & 63;
  int by = blockIdx.x >> 6;
  int tx = threadIdx.x & 31, ty = threadIdx.x >> 5;
  int p0 = bx * 32, c0 = by * 32;
  if (threadIdx.x < 32) pv[threadIdx.x] = pinv[p0 + threadIdx.x];
#pragma unroll
  for (int k = 0; k < 4; ++k)
    tile[ty + 8 * k][tx] = pool[(size_t)(p0 + ty + 8 * k) * C_DIM + c0 + tx];
  __syncthreads();
#pragma unroll
  for (int k = 0; k < 4; ++k)
    poolTs[(size_t)(c0 + ty + 8 * k) * P_DIM + p0 + tx] = tile[tx][ty + 8 * k] * pv[tx];
}

// ---------------- main fused kernel ----------------
// grid = 1024 blocks (16 pixels each), 1024 threads (16 waves).
// thread (tp = t&255, th = t>>8): p-tile [8*tp, 8*tp+8), pixels [4*th, 4*th+4)
__global__ __launch_bounds__(1024, 6) void k_main(const float* __restrict__ x,
                                                  const float* __restrict__ pool,
                                                  const float* __restrict__ poolTs,
                                                  float* __restrict__ out) {
  // one union'd buffer: xs (phase1) / hist (phase2) / kpw (phase5-6)
  __shared__ __align__(16) unsigned char smem[PIXB * HROW * 4];  // 16640 B
  float (*xs)[PIXB] = (float (*)[PIXB])(void*)smem;              // [C_DIM][PIXB]
  unsigned* hist = (unsigned*)(void*)smem;                       // [PIXB][HROW]
  int2 (*kpw)[KEEP + 2] = (int2 (*)[KEEP + 2])(void*)smem;       // [PIXB][KEEP+2]

  __shared__ unsigned pixPrefix[PIXB], pixR[PIXB], pixGT[PIXB], pixE[PIXB];
  __shared__ unsigned kcnt[PIXB], tie_cnt[PIXB];
  __shared__ int tie_p[PIXB][TIE_CAP];
  __shared__ unsigned char tie_keepf[PIXB][TIE_CAP];
  __shared__ float wsum[16][4];
  __shared__ float invS[PIXB];

  const int t = threadIdx.x;
  const int tp = t & 255;
  const int th = t >> 8;    // 0..3
  const int lane = t & 63;
  const int wv = t >> 6;    // 0..15
  const int b = blockIdx.x;
  const int n = b >> 6;
  const int l0 = (b & 63) * PIXB;

  // ---- stage x tile: xs[c][pix] = x[n][c][l0+pix] ----
  {
    int c = t >> 2, q = t & 3;
    float4 v = *(const float4*)(x + ((size_t)(n * C_DIM + c) * L_DIM + l0 + 4 * q));
    *(float4*)&xs[c][4 * q] = v;
  }
  __syncthreads();

  // ---- phase 1: s[j][i] = sum_c poolTs[c][8tp+j] * xs[c][4th+i] ----
  float s[8][4];
#pragma unroll
  for (int j = 0; j < 8; ++j)
#pragma unroll
    for (int i = 0; i < 4; ++i) s[j][i] = 0.f;
  {
    const float* pT = poolTs + 8 * tp;
#pragma unroll 2
    for (int c = 0; c < C_DIM; ++c) {
      float4 pa = *(const float4*)(pT + (size_t)c * P_DIM);
      float4 pb = *(const float4*)(pT + (size_t)c * P_DIM + 4);
      float4 xa = *(const float4*)&xs[c][4 * th];
      float pr[8] = {pa.x, pa.y, pa.z, pa.w, pb.x, pb.y, pb.z, pb.w};
      float xr[4] = {xa.x, xa.y, xa.z, xa.w};
#pragma unroll
      for (int j = 0; j < 8; ++j)
#pragma unroll
        for (int i = 0; i < 4; ++i) s[j][i] = fmaf(pr[j], xr[i], s[j][i]);
    }
  }
  __syncthreads();   // xs dead; smem becomes hist

  // ---- phase 2: 4-pass radix select on |s| bits -> exact threshold ----
  if (t < PIXB) {
    pixPrefix[t] = 0u; pixR[t] = (unsigned)KEEP; pixGT[t] = 0u; pixE[t] = 0u;
    kcnt[t] = 0u; tie_cnt[t] = 0u;
  }
  __syncthreads();

  const unsigned shArr[4] = {23u, 15u, 7u, 0u};
  const unsigned hmArr[4] = {0u, 0x7F800000u, 0x7FFF8000u, 0x7FFFFF80u};
  const unsigned cmArr[4] = {255u, 255u, 255u, 127u};
#pragma unroll 1
  for (int pass = 0; pass < 4; ++pass) {
    for (int idx = t; idx < PIXB * HROW; idx += 1024) hist[idx] = 0u;
    __syncthreads();
    unsigned sh = shArr[pass], hm = hmArr[pass], cmv = cmArr[pass];
#pragma unroll
    for (int i = 0; i < 4; ++i) {
      int pix = 4 * th + i;
      unsigned pref = pixPrefix[pix];
#pragma unroll
      for (int j = 0; j < 8; ++j) {
        unsigned bits = __float_as_uint(fabsf(s[j][i]));
        if ((bits & hm) == pref)
          atomicAdd(&hist[pix * HROW + ((bits >> sh) & cmv)], 1u);  // fire-and-forget
      }
    }
    __syncthreads();
    // wave wv scans pixel wv's 256 bins (4 per lane), descending
    {
      int pix = wv;
      uint4 h4 = *(uint4*)&hist[pix * HROW + 4 * lane];
      unsigned own = h4.x + h4.y + h4.z + h4.w;
      unsigned incl = own;
#pragma unroll
      for (int off = 1; off < 64; off <<= 1) {
        unsigned tmp = __shfl_down(incl, off);
        if (lane + off < 64) incl += tmp;
      }
      unsigned r = pixR[pix];
      unsigned sufx = incl - own;
      if (sufx < r && incl >= r) {     // exactly one lane per pixel
        unsigned hv[4] = {h4.w, h4.z, h4.y, h4.x};
        unsigned cg = sufx, bsel = 0u, hsel = 0u;
        bool found = false;
#pragma unroll
        for (int q = 0; q < 4; ++q) {
          unsigned h = hv[q];
          if (!found) {
            if (cg + h >= r) { found = true; bsel = (unsigned)(4 * lane + 3 - q); hsel = h; }
            else cg += h;
          }
        }
        pixPrefix[pix] |= bsel << sh;
        pixGT[pix] += cg;
        pixR[pix] = r - cg;
        if (pass == 3) pixE[pix] = hsel;
      }
    }
    __syncthreads();
  }

  // ---- phase 3: inclusion mask + exact tie handling (keep smallest p) ----
  unsigned incmask[4];
  bool slow[4];
#pragma unroll
  for (int i = 0; i < 4; ++i) {
    incmask[i] = 0u;
    int pix = 4 * th + i;
    float Vf = __uint_as_float(pixPrefix[pix]);
    slow[i] = (pixE[pix] != pixR[pix]);
#pragma unroll
    for (int j = 0; j < 8; ++j) {
      float av = fabsf(s[j][i]);
      if (av > Vf) incmask[i] |= (1u << j);
      else if (av == Vf) {
        if (!slow[i]) incmask[i] |= (1u << j);
        else {
          unsigned idx = atomicAdd(&tie_cnt[pix], 1u);
          if (idx < TIE_CAP) tie_p[pix][idx] = 8 * tp + j;
        }
      }
    }
  }
  __syncthreads();

  if (t < PIXB) {  // resolve ties: keep r smallest indices among equals
    int pix = t;
    unsigned e = pixE[pix], r = pixR[pix];
    if (e != r) {
      unsigned tc = tie_cnt[pix]; if (tc > TIE_CAP) tc = TIE_CAP;
      for (unsigned k = 0; k < tc; ++k) tie_keepf[pix][k] = 0;
      unsigned rr = (r < tc) ? r : tc;
      for (unsigned k = 0; k < rr; ++k) {
        int best = -1, bp = 1 << 30;
        for (unsigned m = 0; m < tc; ++m)
          if (!tie_keepf[pix][m] && tie_p[pix][m] < bp) { bp = tie_p[pix][m]; best = (int)m; }
        if (best >= 0) tie_keepf[pix][best] = 1;
      }
    }
  }
  __syncthreads();

#pragma unroll
  for (int i = 0; i < 4; ++i) {
    if (slow[i]) {
      int pix = 4 * th + i;
      float Vf = __uint_as_float(pixPrefix[pix]);
      unsigned tc = tie_cnt[pix]; if (tc > TIE_CAP) tc = TIE_CAP;
#pragma unroll
      for (int j = 0; j < 8; ++j) {
        if (fabsf(s[j][i]) == Vf) {
          int myp = 8 * tp + j;
          for (unsigned m = 0; m < tc; ++m)
            if (tie_p[pix][m] == myp && tie_keepf[pix][m]) incmask[i] |= (1u << j);
        }
      }
    }
  }

  // ---- phase 4: S = sum of kept s (signed), invS ----
  float ps[4];
#pragma unroll
  for (int i = 0; i < 4; ++i) {
    float a = 0.f;
#pragma unroll
    for (int j = 0; j < 8; ++j)
      if (incmask[i] & (1u << j)) a += s[j][i];
    ps[i] = a;
  }
#pragma unroll
  for (int off = 32; off > 0; off >>= 1) {
#pragma unroll
    for (int i = 0; i < 4; ++i) ps[i] += __shfl_down(ps[i], off);
  }
  if (lane == 0) {
#pragma unroll
    for (int i = 0; i < 4; ++i) wsum[wv][i] = ps[i];
  }
  __syncthreads();  // wsum ready; hist reads done -> smem becomes kpw
  if (t < PIXB) {
    int pix = t, g = pix >> 2, i = pix & 3;
    float S = 0.f;
    for (int w = 4 * g; w < 4 * g + 4; ++w) S += wsum[w][i];
    invS[pix] = 1.0f / S;
  }

  // ---- phase 5: gather kept (p, s) into LDS lists ----
#pragma unroll
  for (int i = 0; i < 4; ++i) {
    int pix = 4 * th + i;
#pragma unroll
    for (int j = 0; j < 8; ++j) {
      if (incmask[i] & (1u << j)) {
        unsigned idx = atomicAdd(&kcnt[pix], 1u);
        if (idx < KEEP + 2) kpw[pix][idx] = make_int2(8 * tp + j, __float_as_int(s[j][i]));
      }
    }
  }
  __syncthreads();

  // ---- phase 6: out[n][c=tp][pix] = invS * sum_kept s_p * pool[p][c] ----
  float oacc[4];
  unsigned kc[4];
#pragma unroll
  for (int i = 0; i < 4; ++i) {
    oacc[i] = 0.f;
    unsigned kk = kcnt[4 * th + i];
    kc[i] = kk < (unsigned)KEEP ? kk : (unsigned)KEEP;
  }
  const float* pbase = pool + tp;
  int2 e[4];
#pragma unroll
  for (int i = 0; i < 4; ++i) e[i] = kpw[4 * th + i][0];
#pragma unroll 2
  for (int k = 0; k < KEEP; ++k) {
    int2 en[4];
#pragma unroll
    for (int i = 0; i < 4; ++i) en[i] = kpw[4 * th + i][k + 1];  // row padded; garbage ok
#pragma unroll
    for (int i = 0; i < 4; ++i) {
      float pv = pbase[(size_t)(e[i].x & (P_DIM - 1)) * C_DIM];
      if ((unsigned)k < kc[i]) oacc[i] = fmaf(__int_as_float(e[i].y), pv, oacc[i]);
    }
#pragma unroll
    for (int i = 0; i < 4; ++i) e[i] = en[i];
  }
#pragma unroll
  for (int i = 0; i < 4; ++i) oacc[i] *= invS[4 * th + i];
  float* dst = out + ((size_t)(n * C_DIM + tp) * L_DIM + l0 + 4 * th);
  *(float4*)dst = make_float4(oacc[0], oacc[1], oacc[2], oacc[3]);
}

// ---------------- launch ----------------
extern "C" void kernel_launch(void* const* d_in, const int* in_sizes, int n_in,
                              void* d_out, int out_size, void* d_ws, size_t ws_size,
                              hipStream_t stream) {
  const float* x = (const float*)d_in[0];
  const float* pool = (const float*)d_in[1];
  float* out = (float*)d_out;
  float* poolTs = (float*)d_ws;                       // 2 MB
  float* pinv = poolTs + (size_t)C_DIM * P_DIM;       // + 8 KB
  k_pinv<<<P_DIM / 256, 256, 0, stream>>>(pool, pinv);
  k_transpose<<<(P_DIM / 32) * (C_DIM / 32), 256, 0, stream>>>(pool, pinv, poolTs);
  k_main<<<(N_DIM * L_DIM) / PIXB, 1024, 0, stream>>>(x, pool, poolTs, out);
}

// Round 3
// 404.015 us; speedup vs baseline: 2.8314x; 1.9218x over previous
//
#include <hip/hip_runtime.h>

#define C_DIM 256
#define P_DIM 2048
#define L_DIM 1024
#define N_DIM 16
#define KEEP 102

// ---------------- kernel 1a: pinv[p] = 1/||pool_p|| ----------------
__global__ __launch_bounds__(256) void k_pinv(const float* __restrict__ pool,
                                              float* __restrict__ pinv) {
  int p = blockIdx.x * 256 + threadIdx.x;
  const float4* row = (const float4*)(pool + (size_t)p * C_DIM);
  float s = 0.f;
#pragma unroll
  for (int i = 0; i < C_DIM / 4; ++i) {
    float4 v = row[i];
    s += v.x * v.x + v.y * v.y + v.z * v.z + v.w * v.w;
  }
  pinv[p] = 1.0f / sqrtf(s);
}

// ------------- kernel 1b: poolTs[c][p] = pool[p][c] * pinv[p] -------------
__global__ __launch_bounds__(256) void k_transpose(const float* __restrict__ pool,
                                                   const float* __restrict__ pinv,
                                                   float* __restrict__ poolTs) {
  __shared__ float tile[32][33];
  __shared__ float pv[32];
  int bx = blockIdx.x & 63;
  int by = blockIdx.x >> 6;
  int tx = threadIdx.x & 31, ty = threadIdx.x >> 5;
  int p0 = bx * 32, c0 = by * 32;
  if (threadIdx.x < 32) pv[threadIdx.x] = pinv[p0 + threadIdx.x];
#pragma unroll
  for (int k = 0; k < 4; ++k)
    tile[ty + 8 * k][tx] = pool[(size_t)(p0 + ty + 8 * k) * C_DIM + c0 + tx];
  __syncthreads();
#pragma unroll
  for (int k = 0; k < 4; ++k)
    poolTs[(size_t)(c0 + ty + 8 * k) * P_DIM + p0 + tx] = tile[tx][ty + 8 * k] * pv[tx];
}

// ---------------- kernel A: sbuf[pix][p] = sum_c poolTs[c][p] * x[n][c][l] ----
// 128x128 tile, K=256, 256 threads, 8x8 accumulators per thread.
__global__ __launch_bounds__(256) void k_gemm(const float* __restrict__ poolTs,
                                              const float* __restrict__ x,
                                              float* __restrict__ sbuf) {
  __shared__ float As[16][128];
  __shared__ float Bs[16][128];
  const int t = threadIdx.x;
  const int tx = t & 15, ty = t >> 4;
  const int pT = blockIdx.x & 15;       // p tile (16)
  const int pixT = blockIdx.x >> 4;     // pixel tile (128)
  const int p0 = pT * 128;
  const int n = pixT >> 3;
  const int l0 = (pixT & 7) * 128;
  const int pix0 = pixT * 128;

  const int r = t >> 5;           // 0..7
  const int c4 = (t & 31) * 4;    // 0..124

  float acc[8][8];
#pragma unroll
  for (int j = 0; j < 8; ++j)
#pragma unroll
    for (int i = 0; i < 8; ++i) acc[j][i] = 0.f;

  for (int k0 = 0; k0 < C_DIM; k0 += 16) {
    const float* gA = poolTs + (size_t)(k0 + r) * P_DIM + p0 + c4;
    const float* gB = x + ((size_t)(n * C_DIM + k0 + r)) * L_DIM + l0 + c4;
    float4 a0v = *(const float4*)gA;
    float4 a1v = *(const float4*)(gA + 8 * P_DIM);
    float4 b0v = *(const float4*)gB;
    float4 b1v = *(const float4*)(gB + 8 * L_DIM);
    __syncthreads();                 // previous tile's reads complete
    *(float4*)&As[r][c4] = a0v;
    *(float4*)&As[r + 8][c4] = a1v;
    *(float4*)&Bs[r][c4] = b0v;
    *(float4*)&Bs[r + 8][c4] = b1v;
    __syncthreads();
#pragma unroll
    for (int kk = 0; kk < 16; ++kk) {
      float4 a0 = *(const float4*)&As[kk][tx * 8];
      float4 a1 = *(const float4*)&As[kk][tx * 8 + 4];
      float4 b0 = *(const float4*)&Bs[kk][ty * 8];
      float4 b1 = *(const float4*)&Bs[kk][ty * 8 + 4];
      float ar[8] = {a0.x, a0.y, a0.z, a0.w, a1.x, a1.y, a1.z, a1.w};
      float br[8] = {b0.x, b0.y, b0.z, b0.w, b1.x, b1.y, b1.z, b1.w};
#pragma unroll
      for (int j = 0; j < 8; ++j)
#pragma unroll
        for (int i = 0; i < 8; ++i) acc[j][i] = fmaf(ar[j], br[i], acc[j][i]);
    }
  }

#pragma unroll
  for (int i = 0; i < 8; ++i) {
    float* dst = sbuf + (size_t)(pix0 + ty * 8 + i) * P_DIM + p0 + tx * 8;
    *(float4*)dst = make_float4(acc[0][i], acc[1][i], acc[2][i], acc[3][i]);
    *(float4*)(dst + 4) = make_float4(acc[4][i], acc[5][i], acc[6][i], acc[7][i]);
  }
}

// ---------------- kernel B: per-pixel top-102 select + renorm + recon ----
// 1024 threads = 16 waves; wave wv owns pixel l0+wv. 1024 blocks.
__global__ __launch_bounds__(1024, 4) void k_select(const float* __restrict__ sbuf,
                                                    const float* __restrict__ pool,
                                                    float* __restrict__ out) {
  __shared__ float tbuf[16][260];     // [pix][c] transpose buffer
  __shared__ int2 kpw[16][KEEP];      // kept (p, weight-bits) per pixel

  const int t = threadIdx.x;
  const int lane = t & 63;
  const int wv = t >> 6;              // local pixel 0..15
  const int b = blockIdx.x;
  const int n = b >> 6;
  const int l0 = (b & 63) * 16;
  const size_t pix = (size_t)(n * L_DIM + l0 + wv);
  const float* sp = sbuf + pix * P_DIM;

  // load this pixel's 2048 scores: value (q,rr) has p = q*256 + lane*4 + rr
  float4 v[8];
#pragma unroll
  for (int q = 0; q < 8; ++q) v[q] = *(const float4*)(sp + q * 256 + lane * 4);

  // ---- exact binary search on positive-float bit pattern (31 rounds) ----
  unsigned lo = 0u, hi = 0x7F800000u;
  for (int it = 0; it < 31; ++it) {
    unsigned m = lo + ((hi - lo) >> 1);
    float mf = __uint_as_float(m);
    unsigned cnt = 0;
#pragma unroll
    for (int q = 0; q < 8; ++q) {
      cnt += (fabsf(v[q].x) >= mf) ? 1u : 0u;
      cnt += (fabsf(v[q].y) >= mf) ? 1u : 0u;
      cnt += (fabsf(v[q].z) >= mf) ? 1u : 0u;
      cnt += (fabsf(v[q].w) >= mf) ? 1u : 0u;
    }
#pragma unroll
    for (int off = 1; off < 64; off <<= 1) cnt += __shfl_xor(cnt, off);
    if (cnt >= KEEP) lo = m; else hi = m;
  }
  const float V = __uint_as_float(lo);
  const float Vp = __uint_as_float(lo + 1u);   // strictly-greater threshold

  unsigned ge = 0, gt = 0;
#pragma unroll
  for (int q = 0; q < 8; ++q) {
    const float* f = (const float*)&v[q];
#pragma unroll
    for (int rr = 0; rr < 4; ++rr) {
      float av = fabsf(f[rr]);
      ge += (av >= V) ? 1u : 0u;
      gt += (av >= Vp) ? 1u : 0u;
    }
  }
#pragma unroll
  for (int off = 1; off < 64; off <<= 1) {
    ge += __shfl_xor(ge, off);
    gt += __shfl_xor(gt, off);
  }
  const unsigned E = ge - gt;              // count == V
  const unsigned rrem = (unsigned)KEEP - gt;  // how many of the ties to keep

  // ---- per-value masks ----
  unsigned gmask[8], tmask[8];             // strictly-greater / equal-to-V
#pragma unroll
  for (int q = 0; q < 8; ++q) {
    const float* f = (const float*)&v[q];
    unsigned gm = 0, tm = 0;
#pragma unroll
    for (int rr = 0; rr < 4; ++rr) {
      float av = fabsf(f[rr]);
      if (av >= Vp) gm |= (1u << rr);
      else if (av >= V) tm |= (1u << rr);
    }
    gmask[q] = gm; tmask[q] = tm;
  }

  unsigned keepm[8];
  const unsigned long long lowm = (1ull << lane) - 1ull;
  if (E == rrem) {
#pragma unroll
    for (int q = 0; q < 8; ++q) keepm[q] = gmask[q] | tmask[q];
  } else {
    // keep the rrem smallest-p ties (reference tie-break)
    unsigned base = 0;
#pragma unroll
    for (int q = 0; q < 8; ++q) {
      unsigned long long bl[4];
      unsigned tot = 0, mybefore = 0;
#pragma unroll
      for (int rr = 0; rr < 4; ++rr) {
        bl[rr] = __ballot((tmask[q] >> rr) & 1u);
        tot += (unsigned)__popcll(bl[rr]);
        mybefore += (unsigned)__popcll(bl[rr] & lowm);
      }
      unsigned km = gmask[q], cum = 0;
#pragma unroll
      for (int rr = 0; rr < 4; ++rr) {
        if ((tmask[q] >> rr) & 1u) {
          if (base + mybefore + cum < rrem) km |= (1u << rr);
          ++cum;
        }
      }
      keepm[q] = km;
      base += tot;
    }
  }

  // ---- S = signed sum of kept; invS ----
  float S = 0.f;
#pragma unroll
  for (int q = 0; q < 8; ++q) {
    const float* f = (const float*)&v[q];
#pragma unroll
    for (int rr = 0; rr < 4; ++rr)
      if ((keepm[q] >> rr) & 1u) S += f[rr];
  }
#pragma unroll
  for (int off = 1; off < 64; off <<= 1) S += __shfl_xor(S, off);
  const float invS = 1.0f / S;

  // ---- compact kept (p, s*invS) into LDS in ascending-p order ----
  {
    unsigned kb = 0;
#pragma unroll
    for (int q = 0; q < 8; ++q) {
      unsigned long long cb[4];
      unsigned tot = 0, mybefore = 0;
#pragma unroll
      for (int rr = 0; rr < 4; ++rr) {
        cb[rr] = __ballot((keepm[q] >> rr) & 1u);
        tot += (unsigned)__popcll(cb[rr]);
        mybefore += (unsigned)__popcll(cb[rr] & lowm);
      }
      const float* f = (const float*)&v[q];
      unsigned cum = 0;
#pragma unroll
      for (int rr = 0; rr < 4; ++rr) {
        if ((keepm[q] >> rr) & 1u) {
          unsigned pos = kb + mybefore + cum;
          if (pos < (unsigned)KEEP)
            kpw[wv][pos] = make_int2(q * 256 + lane * 4 + rr,
                                     __float_as_int(f[rr] * invS));
          ++cum;
        }
      }
      kb += tot;
    }
  }
  // wave-local producer/consumer: compiler inserts lgkmcnt; no barrier needed
  __builtin_amdgcn_wave_barrier();

  // ---- reconstruct: out_c = sum_kept w * pool[p][c], c = 4*lane+j ----
  float a0 = 0.f, a1 = 0.f, a2 = 0.f, a3 = 0.f;
  const float* pb = pool + 4 * lane;
  int2 e0 = kpw[wv][0];
  int2 e1 = kpw[wv][1];
  for (int k = 0; k < KEEP; k += 2) {
    int2 f0 = (k + 2 < KEEP) ? kpw[wv][k + 2] : make_int2(0, 0);
    int2 f1 = (k + 3 < KEEP) ? kpw[wv][k + 3] : make_int2(0, 0);
    float4 r0 = *(const float4*)(pb + (size_t)e0.x * C_DIM);
    float4 r1 = *(const float4*)(pb + (size_t)e1.x * C_DIM);
    float w0 = __int_as_float(e0.y), w1 = __int_as_float(e1.y);
    a0 = fmaf(w0, r0.x, a0); a1 = fmaf(w0, r0.y, a1);
    a2 = fmaf(w0, r0.z, a2); a3 = fmaf(w0, r0.w, a3);
    a0 = fmaf(w1, r1.x, a0); a1 = fmaf(w1, r1.y, a1);
    a2 = fmaf(w1, r1.z, a2); a3 = fmaf(w1, r1.w, a3);
    e0 = f0; e1 = f1;
  }

  *(float4*)&tbuf[wv][4 * lane] = make_float4(a0, a1, a2, a3);
  __syncthreads();

  // coalesced store: thread t -> c = t>>2, l chunk = t&3
  {
    int c = t >> 2, lq = t & 3;
    float4 o = make_float4(tbuf[4 * lq + 0][c], tbuf[4 * lq + 1][c],
                           tbuf[4 * lq + 2][c], tbuf[4 * lq + 3][c]);
    *(float4*)(out + ((size_t)(n * C_DIM + c)) * L_DIM + l0 + 4 * lq) = o;
  }
}

// ---------------- launch ----------------
extern "C" void kernel_launch(void* const* d_in, const int* in_sizes, int n_in,
                              void* d_out, int out_size, void* d_ws, size_t ws_size,
                              hipStream_t stream) {
  const float* x = (const float*)d_in[0];
  const float* pool = (const float*)d_in[1];
  float* out = (float*)d_out;
  float* poolTs = (float*)d_ws;                          // 2 MB
  float* pinv = poolTs + (size_t)C_DIM * P_DIM;          // + 8 KB
  float* sbuf = pinv + P_DIM;                            // 134.2 MB scores
  k_pinv<<<P_DIM / 256, 256, 0, stream>>>(pool, pinv);
  k_transpose<<<(P_DIM / 32) * (C_DIM / 32), 256, 0, stream>>>(pool, pinv, poolTs);
  k_gemm<<<16 * 128, 256, 0, stream>>>(poolTs, x, sbuf);
  k_select<<<1024, 1024, 0, stream>>>(sbuf, pool, out);
}

// Round 4
// 356.330 us; speedup vs baseline: 3.2103x; 1.1338x over previous
//
#include <hip/hip_runtime.h>

#define C_DIM 256
#define P_DIM 2048
#define L_DIM 1024
#define N_DIM 16
#define KEEP 102

// ---------------- kernel 1a: pinv[p] = 1/||pool_p|| ----------------
__global__ __launch_bounds__(256) void k_pinv(const float* __restrict__ pool,
                                              float* __restrict__ pinv) {
  int p = blockIdx.x * 256 + threadIdx.x;
  const float4* row = (const float4*)(pool + (size_t)p * C_DIM);
  float s = 0.f;
#pragma unroll
  for (int i = 0; i < C_DIM / 4; ++i) {
    float4 v = row[i];
    s += v.x * v.x + v.y * v.y + v.z * v.z + v.w * v.w;
  }
  pinv[p] = 1.0f / sqrtf(s);
}

// ------------- kernel 1b: poolTs[c][p] = pool[p][c] * pinv[p] -------------
__global__ __launch_bounds__(256) void k_transpose(const float* __restrict__ pool,
                                                   const float* __restrict__ pinv,
                                                   float* __restrict__ poolTs) {
  __shared__ float tile[32][33];
  __shared__ float pv[32];
  int bx = blockIdx.x & 63;
  int by = blockIdx.x >> 6;
  int tx = threadIdx.x & 31, ty = threadIdx.x >> 5;
  int p0 = bx * 32, c0 = by * 32;
  if (threadIdx.x < 32) pv[threadIdx.x] = pinv[p0 + threadIdx.x];
#pragma unroll
  for (int k = 0; k < 4; ++k)
    tile[ty + 8 * k][tx] = pool[(size_t)(p0 + ty + 8 * k) * C_DIM + c0 + tx];
  __syncthreads();
#pragma unroll
  for (int k = 0; k < 4; ++k)
    poolTs[(size_t)(c0 + ty + 8 * k) * P_DIM + p0 + tx] = tile[tx][ty + 8 * k] * pv[tx];
}

// ---------------- kernel A: sbuf[pix][p] = sum_c poolTs[c][p] * x[n][c][l] ----
// 128x128 tile, K-step 16, 256 threads, 8x8 acc, split 4+4 microtiles
// (fragment reads at stride 16B -> <=2-way bank aliasing, free).
__global__ __launch_bounds__(256) void k_gemm(const float* __restrict__ poolTs,
                                              const float* __restrict__ x,
                                              float* __restrict__ sbuf) {
  __shared__ float As[16][128];
  __shared__ float Bs[16][128];
  const int t = threadIdx.x;
  const int tx = t & 15, ty = t >> 4;
  const int pT = blockIdx.x & 15;       // p tile (16)
  const int pixT = blockIdx.x >> 4;     // pixel tile (128)
  const int p0 = pT * 128;
  const int n = pixT >> 3;
  const int l0 = (pixT & 7) * 128;
  const int pix0 = pixT * 128;

  const int r = t >> 5;           // 0..7
  const int c4 = (t & 31) * 4;    // 0..124

  float acc[8][8];                // [p-sub][pix-sub]
#pragma unroll
  for (int j = 0; j < 8; ++j)
#pragma unroll
    for (int i = 0; i < 8; ++i) acc[j][i] = 0.f;

  for (int k0 = 0; k0 < C_DIM; k0 += 16) {
    const float* gA = poolTs + (size_t)(k0 + r) * P_DIM + p0 + c4;
    const float* gB = x + ((size_t)(n * C_DIM + k0 + r)) * L_DIM + l0 + c4;
    float4 a0v = *(const float4*)gA;
    float4 a1v = *(const float4*)(gA + 8 * P_DIM);
    float4 b0v = *(const float4*)gB;
    float4 b1v = *(const float4*)(gB + 8 * L_DIM);
    __syncthreads();                 // previous tile's reads complete
    *(float4*)&As[r][c4] = a0v;
    *(float4*)&As[r + 8][c4] = a1v;
    *(float4*)&Bs[r][c4] = b0v;
    *(float4*)&Bs[r + 8][c4] = b1v;
    __syncthreads();
#pragma unroll
    for (int kk = 0; kk < 16; ++kk) {
      float4 a0 = *(const float4*)&As[kk][tx * 4];
      float4 a1 = *(const float4*)&As[kk][64 + tx * 4];
      float4 b0 = *(const float4*)&Bs[kk][ty * 4];
      float4 b1 = *(const float4*)&Bs[kk][64 + ty * 4];
      float ar[8] = {a0.x, a0.y, a0.z, a0.w, a1.x, a1.y, a1.z, a1.w};
      float br[8] = {b0.x, b0.y, b0.z, b0.w, b1.x, b1.y, b1.z, b1.w};
#pragma unroll
      for (int j = 0; j < 8; ++j)
#pragma unroll
        for (int i = 0; i < 8; ++i) acc[j][i] = fmaf(ar[j], br[i], acc[j][i]);
    }
  }

  // stores: pix rows ty*4+i and 64+ty*4+i; p cols tx*4 and 64+tx*4
#pragma unroll
  for (int i = 0; i < 4; ++i) {
    float* dst0 = sbuf + (size_t)(pix0 + ty * 4 + i) * P_DIM + p0;
    *(float4*)(dst0 + tx * 4) = make_float4(acc[0][i], acc[1][i], acc[2][i], acc[3][i]);
    *(float4*)(dst0 + 64 + tx * 4) = make_float4(acc[4][i], acc[5][i], acc[6][i], acc[7][i]);
    float* dst1 = sbuf + (size_t)(pix0 + 64 + ty * 4 + i) * P_DIM + p0;
    *(float4*)(dst1 + tx * 4) = make_float4(acc[0][4 + i], acc[1][4 + i], acc[2][4 + i], acc[3][4 + i]);
    *(float4*)(dst1 + 64 + tx * 4) = make_float4(acc[4][4 + i], acc[5][4 + i], acc[6][4 + i], acc[7][4 + i]);
  }
}

// ---------------- kernel B: per-pixel top-102 select + renorm + recon ----
// 512 threads = 8 waves; wave wv owns pixel l0+wv. 2048 blocks.
// value slot u (0..31): p = (u>>2)*256 + (u&3)*64 + lane  (lane-order == p-order)
__global__ __launch_bounds__(512) void k_select(const float* __restrict__ sbuf,
                                                const float* __restrict__ pool,
                                                float* __restrict__ out) {
  __shared__ __align__(16) float tbuf[8][260];  // [pix][c] transpose buffer
  __shared__ int2 kpw[8][KEEP];                 // kept (p, bits(s)) per pixel

  const int t = threadIdx.x;
  const int lane = t & 63;
  const int wv = t >> 6;               // local pixel 0..7
  const int b = blockIdx.x;
  const int n = b >> 7;
  const int l0 = (b & 127) * 8;
  const float* sp = sbuf + (size_t)(n * L_DIM + l0 + wv) * P_DIM;

  float val[32];
#pragma unroll
  for (int u = 0; u < 32; ++u)
    val[u] = sp[(u >> 2) * 256 + (u & 3) * 64 + lane];

  // ---- exact binary search on positive-float bit pattern (31 rounds),
  //      wave count via ballot+popc (scalar accumulate, no shuffles) ----
  unsigned lo = 0u, hi = 0x7F800000u;
  for (int it = 0; it < 31; ++it) {
    unsigned m = lo + ((hi - lo) >> 1);
    float mf = __uint_as_float(m);
    unsigned cnt = 0;
#pragma unroll
    for (int u = 0; u < 32; ++u)
      cnt += (unsigned)__popcll(__ballot(fabsf(val[u]) >= mf));
    if (cnt >= KEEP) lo = m; else hi = m;
  }
  const float V = __uint_as_float(lo);
  const float Vp = __uint_as_float(lo + 1u);   // strictly-greater threshold

  unsigned gt = 0;
#pragma unroll
  for (int u = 0; u < 32; ++u)
    gt += (unsigned)__popcll(__ballot(fabsf(val[u]) >= Vp));
  const unsigned rrem = (unsigned)KEEP - gt;   // ties to keep (smallest p first)

  // ---- single-pass compaction in ascending-p order; exact tie handling ----
  const unsigned long long lowm = (1ull << lane) - 1ull;
  unsigned base = 0, tiebase = 0;
  float Ssum = 0.f;
#pragma unroll
  for (int u = 0; u < 32; ++u) {
    float av = fabsf(val[u]);
    bool isgt = av >= Vp;
    bool iseq = (av >= V) && !isgt;
    unsigned long long beq = __ballot(iseq);
    unsigned eqrank = tiebase + (unsigned)__popcll(beq & lowm);
    bool keep = isgt || (iseq && eqrank < rrem);
    unsigned long long bk = __ballot(keep);
    if (keep) {
      unsigned pos = base + (unsigned)__popcll(bk & lowm);
      int p = (u >> 2) * 256 + (u & 3) * 64 + lane;
      kpw[wv][pos] = make_int2(p, __float_as_int(val[u]));
      Ssum += val[u];
    }
    base += (unsigned)__popcll(bk);
    tiebase += (unsigned)__popcll(beq);
  }

  // ---- S = signed sum of kept (invS applied at the end) ----
#pragma unroll
  for (int off = 1; off < 64; off <<= 1) Ssum += __shfl_xor(Ssum, off);
  const float invS = 1.0f / Ssum;

  __builtin_amdgcn_wave_barrier();   // wave-local LDS produce->consume

  // ---- reconstruct: out_c = invS * sum_kept s_p * pool[p][c], c=4*lane+j ----
  float a0 = 0.f, a1 = 0.f, a2 = 0.f, a3 = 0.f;
  const float* pb = pool + 4 * lane;
  int2 e0 = kpw[wv][0], e1 = kpw[wv][1];
  float4 r0 = *(const float4*)(pb + (size_t)e0.x * C_DIM);
  float4 r1 = *(const float4*)(pb + (size_t)e1.x * C_DIM);
  for (int k = 0; k < KEEP; k += 2) {
    int kn = (k + 2 < KEEP) ? k + 2 : 0;     // dummy prefetch on last iter
    int2 f0 = kpw[wv][kn], f1 = kpw[wv][kn + 1];
    float4 s0 = *(const float4*)(pb + (size_t)f0.x * C_DIM);
    float4 s1 = *(const float4*)(pb + (size_t)f1.x * C_DIM);
    float w0 = __int_as_float(e0.y), w1 = __int_as_float(e1.y);
    a0 = fmaf(w0, r0.x, a0); a1 = fmaf(w0, r0.y, a1);
    a2 = fmaf(w0, r0.z, a2); a3 = fmaf(w0, r0.w, a3);
    a0 = fmaf(w1, r1.x, a0); a1 = fmaf(w1, r1.y, a1);
    a2 = fmaf(w1, r1.z, a2); a3 = fmaf(w1, r1.w, a3);
    e0 = f0; e1 = f1; r0 = s0; r1 = s1;
  }
  a0 *= invS; a1 *= invS; a2 *= invS; a3 *= invS;

  *(float4*)&tbuf[wv][4 * lane] = make_float4(a0, a1, a2, a3);
  __syncthreads();

  // coalesced store: thread t -> c = t>>1, pixel quad = (t&1)*4
  {
    int c = t >> 1, lq = t & 1;
    float4 o = make_float4(tbuf[4 * lq + 0][c], tbuf[4 * lq + 1][c],
                           tbuf[4 * lq + 2][c], tbuf[4 * lq + 3][c]);
    *(float4*)(out + ((size_t)(n * C_DIM + c)) * L_DIM + l0 + 4 * lq) = o;
  }
}

// ---------------- launch ----------------
extern "C" void kernel_launch(void* const* d_in, const int* in_sizes, int n_in,
                              void* d_out, int out_size, void* d_ws, size_t ws_size,
                              hipStream_t stream) {
  const float* x = (const float*)d_in[0];
  const float* pool = (const float*)d_in[1];
  float* out = (float*)d_out;
  float* poolTs = (float*)d_ws;                          // 2 MB
  float* pinv = poolTs + (size_t)C_DIM * P_DIM;          // + 8 KB
  float* sbuf = pinv + P_DIM;                            // 134.2 MB scores
  k_pinv<<<P_DIM / 256, 256, 0, stream>>>(pool, pinv);
  k_transpose<<<(P_DIM / 32) * (C_DIM / 32), 256, 0, stream>>>(pool, pinv, poolTs);
  k_gemm<<<16 * 128, 256, 0, stream>>>(poolTs, x, sbuf);
  k_select<<<2048, 512, 0, stream>>>(sbuf, pool, out);
}